// Round 3
// 633.451 us; speedup vs baseline: 1.0133x; 1.0133x over previous
//
#include <hip/hip_runtime.h>
#include <hip/hip_bf16.h>
#include <math.h>

// Problem constants
#define BB 16
#define SS 512
#define TT 128
#define EE 256
#define ENC 32
#define DEC 128
#define VOUT 32000

typedef _Float16 half8 __attribute__((ext_vector_type(8)));
typedef float floatx4 __attribute__((ext_vector_type(4)));

__device__ __forceinline__ float sigmoidf_(float x) { return 1.0f / (1.0f + expf(-x)); }
__device__ __forceinline__ float rcpf_(float x) { return __builtin_amdgcn_rcpf(x); }

#define LOG2E 1.4426950408889634f

// ---------------------------------------------------------------------------
// K2: fused source-embedding(+pos-encoding) and input projection for both LSTM
// directions.  Z{f,b}[bs, j] = sum_e src[bs,e] * W{f,b}[e,j] + b{f,b}[j]
// Output layout is PERMUTED for k_scan: col j = half*64 + isB*32 + u is stored
// at position half*64 + 2*u + isB, so scan-lane (half*32+u) reads its two gate
// pre-activations as one float2 at 2*lane.
// grid: 1024 blocks (8 rows each), 256 threads
// ---------------------------------------------------------------------------
__global__ __launch_bounds__(256) void k_embed_gemm(
    const int* __restrict__ source, const float* __restrict__ src_emb,
    const float* __restrict__ Wf, const float* __restrict__ bf,
    const float* __restrict__ Wb, const float* __restrict__ bb,
    float* __restrict__ Zf, float* __restrict__ Zb)
{
    __shared__ __align__(16) float sSrc[8][EE];
    const int r0 = blockIdx.x * 8;
    const int tid = threadIdx.x;

    // stage 8 src rows: emb*sqrt(E) + positional encoding
    for (int idx = tid; idx < 8 * EE; idx += 256) {
        const int r = idx >> 8, e = idx & 255;
        const int row = r0 + r;
        const int s = row & (SS - 1);
        const int tok = source[row];
        float v = src_emb[(size_t)tok * EE + e] * 16.0f;  // sqrt(256)=16
        const int jh = (e < 128) ? e : (e - 128);
        const float rate = expf(-0.07195578415f * (float)jh);  // ln(10000)/128
        const float ang = (float)s * rate;
        v += (e < 128) ? sinf(ang) : cosf(ang);
        sSrc[r][e] = v;
    }
    __syncthreads();

    const int j = tid & 127;
    const float* W = (tid < 128) ? Wf : Wb;
    const float* bv = (tid < 128) ? bf : bb;
    float* Zo = (tid < 128) ? Zf : Zb;

    float acc[8];
    const float bias = bv[j];
#pragma unroll
    for (int r = 0; r < 8; ++r) acc[r] = bias;

    for (int e = 0; e < EE; e += 4) {
        const float w0 = W[(e + 0) * 128 + j];
        const float w1 = W[(e + 1) * 128 + j];
        const float w2 = W[(e + 2) * 128 + j];
        const float w3 = W[(e + 3) * 128 + j];
#pragma unroll
        for (int r = 0; r < 8; ++r) {
            const float4 x = *(const float4*)&sSrc[r][e];
            acc[r] = fmaf(x.x, w0, acc[r]);
            acc[r] = fmaf(x.y, w1, acc[r]);
            acc[r] = fmaf(x.z, w2, acc[r]);
            acc[r] = fmaf(x.w, w3, acc[r]);
        }
    }
    // permuted column: j = half*64 + isB*32 + u  ->  half*64 + 2u + isB
    const int jperm = ((j >> 6) << 6) | ((j & 31) << 1) | ((j >> 5) & 1);
#pragma unroll
    for (int r = 0; r < 8; ++r) Zo[(size_t)(r0 + r) * 128 + jperm] = acc[r];
}

// ---------------------------------------------------------------------------
// K3: wave-level LSTM scan.  One 64-lane wave per (batch, direction); no LDS
// tiles, no barriers.  lane = (half, u): half0 computes gates i,f of unit u;
// half1 computes g,o.  h lives in lanes 0..31; broadcast via v_readlane;
// cross-half combine via __shfl_xor(.,32) (baseline-proven; ds_bpermute).
// Z rows are pre-permuted so each lane loads its (A,B) pair as one dwordx2,
// with a 4-deep rotating register prefetch (loads ~4 steps ahead).
// grid: 32 blocks, 64 threads.
// ---------------------------------------------------------------------------
__global__ __launch_bounds__(64) void k_scan(
    const float* __restrict__ Zf, const float* __restrict__ Zb,
    const float* __restrict__ Uf, const float* __restrict__ Ub,
    float* __restrict__ enc, float* __restrict__ hidden)
{
    const int blk = blockIdx.x;
    const int batch = blk >> 1;
    const int dir = blk & 1;
    const float* __restrict__ Z = dir ? Zb : Zf;
    const float* __restrict__ U = dir ? Ub : Uf;
    const int lane = threadIdx.x;
    const int u = lane & 31;
    const int half = lane >> 5;
    const int colA = half * 64 + u;        // half0: i, half1: g
    const int colB = half * 64 + 32 + u;   // half0: f, half1: o

    float uA[ENC], uB[ENC];
#pragma unroll
    for (int k = 0; k < ENC; ++k) {
        uA[k] = U[k * 128 + colA];
        uB[k] = U[k * 128 + colB];
    }

    const int dt = dir ? -1 : 1;
    const int t0 = dir ? (SS - 1) : 0;
    const int dstep = dt * 128;            // float stride per timestep
    const float* __restrict__ Zbase = Z + (size_t)batch * (SS * 128) + 2 * lane;
    int zoff = t0 * 128;                   // float offset of CURRENT row

    // 4-deep prefetch ring (statically indexed — rule #20).  The last group's
    // prefetches read up to 4 rows past either end of this direction's Z
    // array; those addresses stay inside the Zf/Zb workspace block and the
    // values are never consumed.
    float2 z0 = *(const float2*)(Zbase + zoff);
    float2 z1 = *(const float2*)(Zbase + zoff + dstep);
    float2 z2 = *(const float2*)(Zbase + zoff + 2 * dstep);
    float2 z3 = *(const float2*)(Zbase + zoff + 3 * dstep);

    float* __restrict__ ep = enc + ((size_t)batch * SS + t0) * 64 + dir * ENC + u;
    const int estep = dt * 64;

    const float m = half ? 2.0f : 1.0f;    // half1's gate-A is tanh = 2*sig(2x)-1
    const float madd = half ? -1.0f : 0.0f;
    const float mk = -LOG2E * m;           // exp(-m*x) == exp2(mk*x)

    float h = 0.0f, c = 0.0f;

#define LSTM_STEP(ZS)                                                          \
    do {                                                                       \
        float accA0 = ZS.x, accA1 = 0.f, accA2 = 0.f, accA3 = 0.f;             \
        float accB0 = ZS.y, accB1 = 0.f, accB2 = 0.f, accB3 = 0.f;             \
        ZS = *(const float2*)(Zbase + zoff + 4 * dstep); /* prefetch t+4 */    \
        _Pragma("unroll")                                                      \
        for (int k = 0; k < ENC; k += 4) {                                     \
            const float h0 = __builtin_bit_cast(float,                         \
                __builtin_amdgcn_readlane(__builtin_bit_cast(int, h), k + 0)); \
            const float h1 = __builtin_bit_cast(float,                         \
                __builtin_amdgcn_readlane(__builtin_bit_cast(int, h), k + 1)); \
            const float h2 = __builtin_bit_cast(float,                         \
                __builtin_amdgcn_readlane(__builtin_bit_cast(int, h), k + 2)); \
            const float h3 = __builtin_bit_cast(float,                         \
                __builtin_amdgcn_readlane(__builtin_bit_cast(int, h), k + 3)); \
            accA0 = fmaf(h0, uA[k + 0], accA0);                                \
            accB0 = fmaf(h0, uB[k + 0], accB0);                                \
            accA1 = fmaf(h1, uA[k + 1], accA1);                                \
            accB1 = fmaf(h1, uB[k + 1], accB1);                                \
            accA2 = fmaf(h2, uA[k + 2], accA2);                                \
            accB2 = fmaf(h2, uB[k + 2], accB2);                                \
            accA3 = fmaf(h3, uA[k + 3], accA3);                                \
            accB3 = fmaf(h3, uB[k + 3], accB3);                                \
        }                                                                      \
        const float zAv = (accA0 + accA1) + (accA2 + accA3);                   \
        const float zBv = (accB0 + accB1) + (accB2 + accB3);                   \
        /* half0 a1=sig(zA), half1 a1=tanh(zA)=2*sig(2zA)-1; a2=sig(zB) */     \
        const float s1 = rcpf_(1.0f + __builtin_amdgcn_exp2f(mk * zAv));       \
        const float a1 = fmaf(s1, m, madd);                                    \
        const float a2 = rcpf_(1.0f + __builtin_amdgcn_exp2f(-LOG2E * zBv));   \
        /* cross-half exchange: half0 receives (tanh_g, sig_o) from half1 */   \
        const float t1 = __shfl_xor(a1, 32);                                   \
        const float t2 = __shfl_xor(a2, 32);                                   \
        /* half0: c = sig_f*c + sig_i*tanh_g ; h = sig_o*tanh(c) */            \
        c = fmaf(a2, c, a1 * t1);                                              \
        const float e2 = __builtin_amdgcn_exp2f(-2.0f * LOG2E * c);            \
        const float tc = (1.0f - e2) * rcpf_(1.0f + e2);                       \
        h = t2 * tc;                       /* valid in lanes 0..31 only */     \
        if (half == 0) *ep = h;                                                \
        ep += estep;                                                           \
        zoff += dstep;                                                         \
    } while (0)

    for (int grp = 0; grp < SS / 4; ++grp) {
        LSTM_STEP(z0);
        LSTM_STEP(z1);
        LSTM_STEP(z2);
        LSTM_STEP(z3);
    }
#undef LSTM_STEP

    if (half == 0)
        hidden[batch * 64 + dir * ENC + u] = h;
}

// ---------------------------------------------------------------------------
// K4a: q2[b,d] = hidden[b,:] @ W1[:,d] + b1[d] + b2[d]   (grid 16, 128 thr)
// ---------------------------------------------------------------------------
__global__ __launch_bounds__(128) void k_q(
    const float* __restrict__ hidden, const float* __restrict__ W1,
    const float* __restrict__ b1, const float* __restrict__ b2,
    float* __restrict__ q2)
{
    const int b = blockIdx.x, d = threadIdx.x;
    __shared__ __align__(16) float shid[64];
    if (d < 64) shid[d] = hidden[b * 64 + d];
    __syncthreads();
    float acc = b1[d] + b2[d];
#pragma unroll
    for (int k = 0; k < 64; k += 4) {
        const float4 h4 = *(const float4*)&shid[k];
        acc = fmaf(h4.x, W1[(k + 0) * 128 + d], acc);
        acc = fmaf(h4.y, W1[(k + 1) * 128 + d], acc);
        acc = fmaf(h4.z, W1[(k + 2) * 128 + d], acc);
        acc = fmaf(h4.w, W1[(k + 3) * 128 + d], acc);
    }
    q2[b * 128 + d] = acc;
}

// ---------------------------------------------------------------------------
// K4b: scores[bs] = tanh(q2[b,:] + enc[bs,:]@W2) @ Vw + Vb  (grid 8192, 128 thr)
// ---------------------------------------------------------------------------
__global__ __launch_bounds__(128) void k_score(
    const float* __restrict__ enc, const float* __restrict__ q2,
    const float* __restrict__ W2, const float* __restrict__ Vw,
    const float* __restrict__ Vb, float* __restrict__ scores)
{
    const int bs = blockIdx.x;
    const int b = bs >> 9;
    const int tid = threadIdx.x;
    __shared__ __align__(16) float se[64];
    __shared__ float sred2[2];
    if (tid < 64) se[tid] = enc[(size_t)bs * 64 + tid];
    __syncthreads();
    float acc = q2[b * 128 + tid];
#pragma unroll
    for (int k = 0; k < 64; k += 4) {
        const float4 e4 = *(const float4*)&se[k];
        acc = fmaf(e4.x, W2[(k + 0) * 128 + tid], acc);
        acc = fmaf(e4.y, W2[(k + 1) * 128 + tid], acc);
        acc = fmaf(e4.z, W2[(k + 2) * 128 + tid], acc);
        acc = fmaf(e4.w, W2[(k + 3) * 128 + tid], acc);
    }
    float v = tanhf(acc) * Vw[tid];
#pragma unroll
    for (int off = 32; off > 0; off >>= 1) v += __shfl_down(v, off);
    if ((tid & 63) == 0) sred2[tid >> 6] = v;
    __syncthreads();
    if (tid == 0) scores[bs] = sred2[0] + sred2[1] + Vb[0];
}

// ---------------------------------------------------------------------------
// K4c: softmax over S + context vector.  grid 16 blocks, 512 threads.
// ---------------------------------------------------------------------------
__global__ __launch_bounds__(512) void k_softmax_ctx(
    const float* __restrict__ scores, const float* __restrict__ enc,
    float* __restrict__ ctx)
{
    const int b = blockIdx.x, tid = threadIdx.x;
    __shared__ float sw[SS];
    __shared__ float sred[SS];
    const float sc = scores[b * SS + tid];
    sred[tid] = sc;
    __syncthreads();
    for (int s2 = 256; s2 > 0; s2 >>= 1) {
        if (tid < s2) sred[tid] = fmaxf(sred[tid], sred[tid + s2]);
        __syncthreads();
    }
    const float mx = sred[0];
    __syncthreads();
    const float ex = expf(sc - mx);
    sw[tid] = ex;
    sred[tid] = ex;
    __syncthreads();
    for (int s2 = 256; s2 > 0; s2 >>= 1) {
        if (tid < s2) sred[tid] += sred[tid + s2];
        __syncthreads();
    }
    const float inv = 1.0f / sred[0];
    __syncthreads();
    const int d = tid & 63, chunk = tid >> 6;
    float acc = 0.0f;
    const int sbeg = chunk * 64;
    for (int s = sbeg; s < sbeg + 64; ++s)
        acc = fmaf(sw[s], enc[((size_t)b * SS + s) * 64 + d], acc);
    sred[tid] = acc * inv;
    __syncthreads();
    if (tid < 64) {
        float t = 0.0f;
#pragma unroll
        for (int c = 0; c < 8; ++c) t += sred[c * 64 + tid];
        ctx[b * 64 + tid] = t;
    }
}

// ---------------------------------------------------------------------------
// K5: decoder gates (forget gate inert since c0=0): Ah[bt,u] =
//   fp16( sig(z_o)*tanh(sig(z_i)*tanh(z_g)) ),  z = [ctx,temb] @ Wd + bd
// grid 256 blocks (8 timesteps each), 384 threads (3 gates x 128 units)
// ---------------------------------------------------------------------------
__global__ __launch_bounds__(384) void k_dec(
    const int* __restrict__ target, const float* __restrict__ tgt_emb,
    const float* __restrict__ ctx, const float* __restrict__ Wd,
    const float* __restrict__ bd, unsigned short* __restrict__ Ah)
{
    const int bt0 = blockIdx.x * 8;
    const int tid = threadIdx.x;
    __shared__ __align__(16) float sx[8][320];
    __shared__ float sg[3][8][128];

    for (int idx = tid; idx < 8 * 320; idx += 384) {
        const int r = idx / 320, k = idx % 320;
        const int bt = bt0 + r;
        const int b = bt >> 7;
        float v;
        if (k < 64) v = ctx[b * 64 + k];
        else v = tgt_emb[(size_t)target[bt] * EE + (k - 64)];
        sx[r][k] = v;
    }
    __syncthreads();

    const int g = tid >> 7, u = tid & 127;
    const int col = (g == 0) ? u : ((g == 1) ? (256 + u) : (384 + u));
    float acc[8];
    const float bias = bd[col];
#pragma unroll
    for (int r = 0; r < 8; ++r) acc[r] = bias;

#pragma unroll 2
    for (int k = 0; k < 320; k += 4) {
        const float w0 = Wd[(k + 0) * 512 + col];
        const float w1 = Wd[(k + 1) * 512 + col];
        const float w2 = Wd[(k + 2) * 512 + col];
        const float w3 = Wd[(k + 3) * 512 + col];
#pragma unroll
        for (int r = 0; r < 8; ++r) {
            const float4 x = *(const float4*)&sx[r][k];
            acc[r] = fmaf(x.x, w0, acc[r]);
            acc[r] = fmaf(x.y, w1, acc[r]);
            acc[r] = fmaf(x.z, w2, acc[r]);
            acc[r] = fmaf(x.w, w3, acc[r]);
        }
    }
#pragma unroll
    for (int r = 0; r < 8; ++r) {
        const float a = acc[r];
        sg[g][r][u] = (g == 1) ? tanhf(a) : sigmoidf_(a);
    }
    __syncthreads();
    if (tid < 128) {
#pragma unroll
        for (int r = 0; r < 8; ++r) {
            const float i_ = sg[0][r][u];
            const float g_ = sg[1][r][u];
            const float o_ = sg[2][r][u];
            const float h = o_ * tanhf(i_ * g_);
            Ah[(size_t)(bt0 + r) * 128 + u] =
                __builtin_bit_cast(unsigned short, (_Float16)h);
        }
    }
}

// ---------------------------------------------------------------------------
// K6a: transpose + fp16-convert Wfc (128 x 32000, N-contig)
//      -> Bt (32000 x 128 fp16, K-contig).  grid 500 blocks, 256 threads.
// ---------------------------------------------------------------------------
__global__ __launch_bounds__(256) void k_cvtB(
    const float* __restrict__ Wfc, unsigned short* __restrict__ Bt)
{
    __shared__ __align__(16) unsigned short sH[64][136];
    const int n0 = blockIdx.x * 64;
    const int tid = threadIdx.x;
    const int kk = tid >> 4;       // 0..15
    const int n4 = tid & 15;       // 0..15

#pragma unroll
    for (int p = 0; p < 8; ++p) {
        const int k = p * 16 + kk;
        const float4 v = *(const float4*)&Wfc[(size_t)k * VOUT + n0 + n4 * 4];
        sH[n4 * 4 + 0][k] = __builtin_bit_cast(unsigned short, (_Float16)v.x);
        sH[n4 * 4 + 1][k] = __builtin_bit_cast(unsigned short, (_Float16)v.y);
        sH[n4 * 4 + 2][k] = __builtin_bit_cast(unsigned short, (_Float16)v.z);
        sH[n4 * 4 + 3][k] = __builtin_bit_cast(unsigned short, (_Float16)v.w);
    }
    __syncthreads();

    const int r0 = tid >> 4;
    const int l8 = (tid & 15) * 8;
#pragma unroll
    for (int p = 0; p < 4; ++p) {
        const int r = p * 16 + r0;
        *(uint4*)&Bt[(size_t)(n0 + r) * 128 + l8] = *(const uint4*)&sH[r][l8];
    }
}

// ---------------------------------------------------------------------------
// K6b: output GEMM  C(2048,32000) = Ah(2048,128) @ Bt^T + bfc, f16 MFMA.
// Block tile 128x128, 4 waves (2x2), each wave 64x64 = 4x4 tiles of 16x16.
// ---------------------------------------------------------------------------
__global__ __launch_bounds__(256) void k_out_f16(
    const unsigned short* __restrict__ Ah,   // 2048 x 128 fp16
    const unsigned short* __restrict__ Bt,   // 32000 x 128 fp16
    const float* __restrict__ bias, float* __restrict__ C)
{
    const int tid  = threadIdx.x;
    const int wave = tid >> 6;
    const int lane = tid & 63;
    const int wm = wave >> 1, wn = wave & 1;
    const int rb = blockIdx.y * 128 + wm * 64;
    const int cb = blockIdx.x * 128 + wn * 64;
    const int lm = lane & 15;
    const int quad = lane >> 4;

    floatx4 acc[4][4];
#pragma unroll
    for (int nt = 0; nt < 4; ++nt) {
        const float bv = bias[cb + nt * 16 + lm];
#pragma unroll
        for (int mt = 0; mt < 4; ++mt)
            acc[mt][nt] = (floatx4){bv, bv, bv, bv};
    }

    const unsigned short* pA = Ah + (size_t)(rb + lm) * 128 + quad * 8;
    const unsigned short* pB = Bt + (size_t)(cb + lm) * 128 + quad * 8;

#pragma unroll
    for (int kc = 0; kc < 128; kc += 32) {
        half8 af[4], bfr[4];
#pragma unroll
        for (int mt = 0; mt < 4; ++mt)
            af[mt] = *(const half8*)(pA + mt * (16 * 128) + kc);
#pragma unroll
        for (int nt = 0; nt < 4; ++nt)
            bfr[nt] = *(const half8*)(pB + nt * (16 * 128) + kc);
#pragma unroll
        for (int mt = 0; mt < 4; ++mt)
#pragma unroll
            for (int nt = 0; nt < 4; ++nt)
                acc[mt][nt] = __builtin_amdgcn_mfma_f32_16x16x32_f16(
                    af[mt], bfr[nt], acc[mt][nt], 0, 0, 0);
    }

#pragma unroll
    for (int mt = 0; mt < 4; ++mt) {
        const int r0 = rb + mt * 16 + quad * 4;
#pragma unroll
        for (int nt = 0; nt < 4; ++nt) {
            const int col = cb + nt * 16 + lm;
            float* Cp = C + (size_t)r0 * VOUT + col;
#pragma unroll
            for (int r = 0; r < 4; ++r)
                Cp[(size_t)r * VOUT] = acc[mt][nt][r];
        }
    }
}

// ---------------------------------------------------------------------------
extern "C" void kernel_launch(void* const* d_in, const int* in_sizes, int n_in,
                              void* d_out, int out_size, void* d_ws, size_t ws_size,
                              hipStream_t stream) {
    (void)in_sizes; (void)n_in; (void)out_size; (void)ws_size;
    const int*   source  = (const int*)  d_in[0];
    const int*   target  = (const int*)  d_in[1];
    const float* src_emb = (const float*)d_in[2];
    const float* tgt_emb = (const float*)d_in[3];
    const float* Wf      = (const float*)d_in[4];
    const float* Uf      = (const float*)d_in[5];
    const float* bf      = (const float*)d_in[6];
    const float* Wb      = (const float*)d_in[7];
    const float* Ub      = (const float*)d_in[8];
    const float* bb      = (const float*)d_in[9];
    const float* W1      = (const float*)d_in[10];
    const float* b1      = (const float*)d_in[11];
    const float* W2      = (const float*)d_in[12];
    const float* b2      = (const float*)d_in[13];
    const float* Vw      = (const float*)d_in[14];
    const float* Vb      = (const float*)d_in[15];
    const float* Wd      = (const float*)d_in[16];
    const float* bd      = (const float*)d_in[17];
    const float* Wfc     = (const float*)d_in[18];
    const float* bfc     = (const float*)d_in[19];
    float* out = (float*)d_out;

    // workspace layout (float offsets)
    float* ws     = (float*)d_ws;
    float* Zf     = ws;                      // 1048576 f (dead after k_scan)
    float* Zb     = Zf + 1048576;            // 1048576 f (dead after k_scan)
    float* enc    = Zb + 1048576;            // 524288 f
    float* hidden = enc + 524288;            // 1024 f
    float* q2     = hidden + 1024;           // 2048 f
    float* scores = q2 + 2048;               // 8192 f
    float* ctx    = scores + 8192;           // 1024 f
    unsigned short* Ah = (unsigned short*)(ctx + 1024);  // 2048*128 fp16
    unsigned short* Bt = (unsigned short*)Zf;            // aliases dead Zf/Zb

    k_embed_gemm<<<1024, 256, 0, stream>>>(source, src_emb, Wf, bf, Wb, bb, Zf, Zb);
    k_scan<<<32, 64, 0, stream>>>(Zf, Zb, Uf, Ub, enc, hidden);
    k_q<<<16, 128, 0, stream>>>(hidden, W1, b1, b2, q2);
    k_score<<<8192, 128, 0, stream>>>(enc, q2, W2, Vw, Vb, scores);
    k_softmax_ctx<<<16, 512, 0, stream>>>(scores, enc, ctx);
    k_cvtB<<<500, 256, 0, stream>>>(Wfc, Bt);   // after k_scan: Zf/Zb dead
    k_dec<<<256, 384, 0, stream>>>(target, tgt_emb, ctx, Wd, bd, Ah);
    k_out_f16<<<dim3(250, 16), 256, 0, stream>>>(Ah, Bt, bfc, out);
}

// Round 5
// 604.023 us; speedup vs baseline: 1.0627x; 1.0487x over previous
//
#include <hip/hip_runtime.h>
#include <hip/hip_bf16.h>
#include <math.h>

// Problem constants
#define BB 16
#define SS 512
#define TT 128
#define EE 256
#define ENC 32
#define DEC 128
#define VOUT 32000

typedef _Float16 half8 __attribute__((ext_vector_type(8)));
typedef float floatx4 __attribute__((ext_vector_type(4)));
typedef float floatx2 __attribute__((ext_vector_type(2)));

__device__ __forceinline__ float sigmoidf_(float x) { return 1.0f / (1.0f + expf(-x)); }
__device__ __forceinline__ float rcpf_(float x) { return __builtin_amdgcn_rcpf(x); }

#define LOG2E 1.4426950408889634f

// packed 2xf32 fma (v_pk_fma_f32 when the backend selects it; exact same
// per-component fused operation either way)
#if __has_builtin(__builtin_elementwise_fma)
#define FMA2(acc, uu, hs) (acc) = __builtin_elementwise_fma((floatx2){(hs), (hs)}, (uu), (acc))
#else
#define FMA2(acc, uu, hs)                                   \
    do {                                                    \
        (acc).x = fmaf((hs), (uu).x, (acc).x);              \
        (acc).y = fmaf((hs), (uu).y, (acc).y);              \
    } while (0)
#endif

// ---------------------------------------------------------------------------
// K2: fused source-embedding(+pos-encoding) and input projection for both LSTM
// directions.  Z{f,b}[bs, j] = sum_e src[bs,e] * W{f,b}[e,j] + b{f,b}[j]
// Output layout PERMUTED for k_scan's gate regrouping (half0=(i,g), half1=
// (f,o)): col j with u=j&31, halfbit=(j>>5)&1, isB=(j>>6)&1 is stored at
// halfbit*64 + 2*u + isB, so scan-lane (halfbit*32+u) reads its (A,B) gate
// pre-activations as one float2 at 2*lane.
//   j=u      (gate i) -> half0 A     j=64+u (gate g) -> half0 B
//   j=32+u   (gate f) -> half1 A     j=96+u (gate o) -> half1 B
// grid: 1024 blocks (8 rows each), 256 threads
// ---------------------------------------------------------------------------
__global__ __launch_bounds__(256) void k_embed_gemm(
    const int* __restrict__ source, const float* __restrict__ src_emb,
    const float* __restrict__ Wf, const float* __restrict__ bf,
    const float* __restrict__ Wb, const float* __restrict__ bb,
    float* __restrict__ Zf, float* __restrict__ Zb)
{
    __shared__ __align__(16) float sSrc[8][EE];
    const int r0 = blockIdx.x * 8;
    const int tid = threadIdx.x;

    // stage 8 src rows: emb*sqrt(E) + positional encoding
    for (int idx = tid; idx < 8 * EE; idx += 256) {
        const int r = idx >> 8, e = idx & 255;
        const int row = r0 + r;
        const int s = row & (SS - 1);
        const int tok = source[row];
        float v = src_emb[(size_t)tok * EE + e] * 16.0f;  // sqrt(256)=16
        const int jh = (e < 128) ? e : (e - 128);
        const float rate = expf(-0.07195578415f * (float)jh);  // ln(10000)/128
        const float ang = (float)s * rate;
        v += (e < 128) ? sinf(ang) : cosf(ang);
        sSrc[r][e] = v;
    }
    __syncthreads();

    const int j = tid & 127;
    const float* W = (tid < 128) ? Wf : Wb;
    const float* bv = (tid < 128) ? bf : bb;
    float* Zo = (tid < 128) ? Zf : Zb;

    float acc[8];
    const float bias = bv[j];
#pragma unroll
    for (int r = 0; r < 8; ++r) acc[r] = bias;

    for (int e = 0; e < EE; e += 4) {
        const float w0 = W[(e + 0) * 128 + j];
        const float w1 = W[(e + 1) * 128 + j];
        const float w2 = W[(e + 2) * 128 + j];
        const float w3 = W[(e + 3) * 128 + j];
#pragma unroll
        for (int r = 0; r < 8; ++r) {
            const float4 x = *(const float4*)&sSrc[r][e];
            acc[r] = fmaf(x.x, w0, acc[r]);
            acc[r] = fmaf(x.y, w1, acc[r]);
            acc[r] = fmaf(x.z, w2, acc[r]);
            acc[r] = fmaf(x.w, w3, acc[r]);
        }
    }
    // permuted column: halfbit = j bit5, isB = j bit6
    const int jperm = (((j >> 5) & 1) << 6) | ((j & 31) << 1) | ((j >> 6) & 1);
#pragma unroll
    for (int r = 0; r < 8; ++r) Zo[(size_t)(r0 + r) * 128 + jperm] = acc[r];
}

// ---------------------------------------------------------------------------
// K3: wave-level LSTM scan.  One 64-lane wave per (batch, direction); no LDS
// tiles, no barriers.  Gate regrouping: lane = (half, u); half0 computes gates
// (i, g) of unit u and locally forms p = sig(z_i)*tanh(z_g); half1 computes
// (f, o) and owns the state: c = sig_f*c + p_recv, h = sig_o*tanh(c).
// ONE cross-half exchange per step (__shfl_xor of p) instead of two.
// h lives in lanes 32..63; broadcast via v_readlane(32+k).
// Z rows pre-permuted so each lane loads its (A,B) pair as one dwordx2, with
// a 4-deep rotating register prefetch.  Recurrent weights staged interleaved
// float2 so the matvec runs on packed-f32 fma chains.
// grid: 32 blocks, 64 threads.
// ---------------------------------------------------------------------------
__global__ __launch_bounds__(64) void k_scan(
    const float* __restrict__ Zf, const float* __restrict__ Zb,
    const float* __restrict__ Uf, const float* __restrict__ Ub,
    float* __restrict__ enc, float* __restrict__ hidden)
{
    const int blk = blockIdx.x;
    const int batch = blk >> 1;
    const int dir = blk & 1;
    const float* __restrict__ Z = dir ? Zb : Zf;
    const float* __restrict__ U = dir ? Ub : Uf;
    const int lane = threadIdx.x;
    const int u = lane & 31;
    const int half = lane >> 5;
    const int colA = half ? (32 + u) : u;        // half0: i, half1: f
    const int colB = half ? (96 + u) : (64 + u); // half0: g, half1: o

    floatx2 u2[ENC];
#pragma unroll
    for (int k = 0; k < ENC; ++k)
        u2[k] = (floatx2){U[k * 128 + colA], U[k * 128 + colB]};

    const int dt = dir ? -1 : 1;
    const int t0 = dir ? (SS - 1) : 0;
    const int dstep = dt * 128;            // float stride per timestep
    const float* __restrict__ Zbase = Z + (size_t)batch * (SS * 128) + 2 * lane;
    int zoff = t0 * 128;                   // float offset of CURRENT row

    // 4-deep prefetch ring (statically indexed — rule #20).  The last group's
    // prefetches read up to 4 rows past either end of this direction's Z
    // array; those addresses stay inside the Zf/Zb workspace block and the
    // values are never consumed.
    float2 z0 = *(const float2*)(Zbase + zoff);
    float2 z1 = *(const float2*)(Zbase + zoff + dstep);
    float2 z2 = *(const float2*)(Zbase + zoff + 2 * dstep);
    float2 z3 = *(const float2*)(Zbase + zoff + 3 * dstep);

    float* __restrict__ ep = enc + ((size_t)batch * SS + t0) * 64 + dir * ENC + u;
    const int estep = dt * 64;

    // B-chain activation: half0 tanh(zB) = 2*sig(2 zB)-1 ; half1 sig(zB)
    const float mB = half ? 1.0f : 2.0f;
    const float maddB = half ? 0.0f : -1.0f;
    const float mkB = -LOG2E * mB;         // exp(-mB*x) == exp2(mkB*x)

    float h = 0.0f, c = 0.0f;

#define LSTM_STEP(ZS)                                                          \
    do {                                                                       \
        floatx2 ac0 = (floatx2){ZS.x, ZS.y};                                   \
        floatx2 ac1 = (floatx2){0.f, 0.f};                                     \
        floatx2 ac2 = (floatx2){0.f, 0.f};                                     \
        floatx2 ac3 = (floatx2){0.f, 0.f};                                     \
        ZS = *(const float2*)(Zbase + zoff + 4 * dstep); /* prefetch t+4 */    \
        _Pragma("unroll")                                                      \
        for (int k = 0; k < ENC; k += 4) {                                     \
            const float h0 = __builtin_bit_cast(float,                         \
                __builtin_amdgcn_readlane(__builtin_bit_cast(int, h), 32 + k + 0)); \
            const float h1 = __builtin_bit_cast(float,                         \
                __builtin_amdgcn_readlane(__builtin_bit_cast(int, h), 32 + k + 1)); \
            const float h2 = __builtin_bit_cast(float,                         \
                __builtin_amdgcn_readlane(__builtin_bit_cast(int, h), 32 + k + 2)); \
            const float h3 = __builtin_bit_cast(float,                         \
                __builtin_amdgcn_readlane(__builtin_bit_cast(int, h), 32 + k + 3)); \
            FMA2(ac0, u2[k + 0], h0);                                          \
            FMA2(ac1, u2[k + 1], h1);                                          \
            FMA2(ac2, u2[k + 2], h2);                                          \
            FMA2(ac3, u2[k + 3], h3);                                          \
        }                                                                      \
        const floatx2 zv = (ac0 + ac1) + (ac2 + ac3);                          \
        const float zAv = zv.x;                                                \
        const float zBv = zv.y;                                                \
        /* A-chain is sigmoid in both halves */                                \
        const float a1 = rcpf_(1.0f + __builtin_amdgcn_exp2f(-LOG2E * zAv));   \
        /* B-chain: half0 tanh, half1 sigmoid */                               \
        const float sB = rcpf_(1.0f + __builtin_amdgcn_exp2f(mkB * zBv));      \
        const float aB = fmaf(sB, mB, maddB);                                  \
        /* half0: p = sig_i * tanh_g ; ship to half1 */                        \
        const float p = a1 * aB;                                               \
        const float pr = __shfl_xor(p, 32);                                    \
        /* half1: c = sig_f*c + p ; h = sig_o*tanh(c) */                       \
        c = fmaf(a1, c, pr);                                                   \
        const float e2 = __builtin_amdgcn_exp2f(-2.0f * LOG2E * c);            \
        const float tc = (1.0f - e2) * rcpf_(1.0f + e2);                       \
        h = aB * tc;                       /* valid in lanes 32..63 only */    \
        if (half) *ep = h;                                                     \
        ep += estep;                                                           \
        zoff += dstep;                                                         \
    } while (0)

    for (int grp = 0; grp < SS / 4; ++grp) {
        LSTM_STEP(z0);
        LSTM_STEP(z1);
        LSTM_STEP(z2);
        LSTM_STEP(z3);
    }
#undef LSTM_STEP

    if (half)
        hidden[batch * 64 + dir * ENC + u] = h;
}

// ---------------------------------------------------------------------------
// K4a: q2[b,d] = hidden[b,:] @ W1[:,d] + b1[d] + b2[d]   (grid 16, 128 thr)
// ---------------------------------------------------------------------------
__global__ __launch_bounds__(128) void k_q(
    const float* __restrict__ hidden, const float* __restrict__ W1,
    const float* __restrict__ b1, const float* __restrict__ b2,
    float* __restrict__ q2)
{
    const int b = blockIdx.x, d = threadIdx.x;
    __shared__ __align__(16) float shid[64];
    if (d < 64) shid[d] = hidden[b * 64 + d];
    __syncthreads();
    float acc = b1[d] + b2[d];
#pragma unroll
    for (int k = 0; k < 64; k += 4) {
        const float4 h4 = *(const float4*)&shid[k];
        acc = fmaf(h4.x, W1[(k + 0) * 128 + d], acc);
        acc = fmaf(h4.y, W1[(k + 1) * 128 + d], acc);
        acc = fmaf(h4.z, W1[(k + 2) * 128 + d], acc);
        acc = fmaf(h4.w, W1[(k + 3) * 128 + d], acc);
    }
    q2[b * 128 + d] = acc;
}

// ---------------------------------------------------------------------------
// K4b: scores[bs] = tanh(q2[b,:] + enc[bs,:]@W2) @ Vw + Vb  (grid 8192, 128 thr)
// ---------------------------------------------------------------------------
__global__ __launch_bounds__(128) void k_score(
    const float* __restrict__ enc, const float* __restrict__ q2,
    const float* __restrict__ W2, const float* __restrict__ Vw,
    const float* __restrict__ Vb, float* __restrict__ scores)
{
    const int bs = blockIdx.x;
    const int b = bs >> 9;
    const int tid = threadIdx.x;
    __shared__ __align__(16) float se[64];
    __shared__ float sred2[2];
    if (tid < 64) se[tid] = enc[(size_t)bs * 64 + tid];
    __syncthreads();
    float acc = q2[b * 128 + tid];
#pragma unroll
    for (int k = 0; k < 64; k += 4) {
        const float4 e4 = *(const float4*)&se[k];
        acc = fmaf(e4.x, W2[(k + 0) * 128 + tid], acc);
        acc = fmaf(e4.y, W2[(k + 1) * 128 + tid], acc);
        acc = fmaf(e4.z, W2[(k + 2) * 128 + tid], acc);
        acc = fmaf(e4.w, W2[(k + 3) * 128 + tid], acc);
    }
    float v = tanhf(acc) * Vw[tid];
#pragma unroll
    for (int off = 32; off > 0; off >>= 1) v += __shfl_down(v, off);
    if ((tid & 63) == 0) sred2[tid >> 6] = v;
    __syncthreads();
    if (tid == 0) scores[bs] = sred2[0] + sred2[1] + Vb[0];
}

// ---------------------------------------------------------------------------
// K4c: softmax over S + context vector.  grid 16 blocks, 512 threads.
// ---------------------------------------------------------------------------
__global__ __launch_bounds__(512) void k_softmax_ctx(
    const float* __restrict__ scores, const float* __restrict__ enc,
    float* __restrict__ ctx)
{
    const int b = blockIdx.x, tid = threadIdx.x;
    __shared__ float sw[SS];
    __shared__ float sred[SS];
    const float sc = scores[b * SS + tid];
    sred[tid] = sc;
    __syncthreads();
    for (int s2 = 256; s2 > 0; s2 >>= 1) {
        if (tid < s2) sred[tid] = fmaxf(sred[tid], sred[tid + s2]);
        __syncthreads();
    }
    const float mx = sred[0];
    __syncthreads();
    const float ex = expf(sc - mx);
    sw[tid] = ex;
    sred[tid] = ex;
    __syncthreads();
    for (int s2 = 256; s2 > 0; s2 >>= 1) {
        if (tid < s2) sred[tid] += sred[tid + s2];
        __syncthreads();
    }
    const float inv = 1.0f / sred[0];
    __syncthreads();
    const int d = tid & 63, chunk = tid >> 6;
    float acc = 0.0f;
    const int sbeg = chunk * 64;
    for (int s = sbeg; s < sbeg + 64; ++s)
        acc = fmaf(sw[s], enc[((size_t)b * SS + s) * 64 + d], acc);
    sred[tid] = acc * inv;
    __syncthreads();
    if (tid < 64) {
        float t = 0.0f;
#pragma unroll
        for (int c = 0; c < 8; ++c) t += sred[c * 64 + tid];
        ctx[b * 64 + tid] = t;
    }
}

// ---------------------------------------------------------------------------
// K5: decoder gates (forget gate inert since c0=0): Ah[bt,u] =
//   fp16( sig(z_o)*tanh(sig(z_i)*tanh(z_g)) ),  z = [ctx,temb] @ Wd + bd
// grid 256 blocks (8 timesteps each), 384 threads (3 gates x 128 units)
// ---------------------------------------------------------------------------
__global__ __launch_bounds__(384) void k_dec(
    const int* __restrict__ target, const float* __restrict__ tgt_emb,
    const float* __restrict__ ctx, const float* __restrict__ Wd,
    const float* __restrict__ bd, unsigned short* __restrict__ Ah)
{
    const int bt0 = blockIdx.x * 8;
    const int tid = threadIdx.x;
    __shared__ __align__(16) float sx[8][320];
    __shared__ float sg[3][8][128];

    for (int idx = tid; idx < 8 * 320; idx += 384) {
        const int r = idx / 320, k = idx % 320;
        const int bt = bt0 + r;
        const int b = bt >> 7;
        float v;
        if (k < 64) v = ctx[b * 64 + k];
        else v = tgt_emb[(size_t)target[bt] * EE + (k - 64)];
        sx[r][k] = v;
    }
    __syncthreads();

    const int g = tid >> 7, u = tid & 127;
    const int col = (g == 0) ? u : ((g == 1) ? (256 + u) : (384 + u));
    float acc[8];
    const float bias = bd[col];
#pragma unroll
    for (int r = 0; r < 8; ++r) acc[r] = bias;

#pragma unroll 2
    for (int k = 0; k < 320; k += 4) {
        const float w0 = Wd[(k + 0) * 512 + col];
        const float w1 = Wd[(k + 1) * 512 + col];
        const float w2 = Wd[(k + 2) * 512 + col];
        const float w3 = Wd[(k + 3) * 512 + col];
#pragma unroll
        for (int r = 0; r < 8; ++r) {
            const float4 x = *(const float4*)&sx[r][k];
            acc[r] = fmaf(x.x, w0, acc[r]);
            acc[r] = fmaf(x.y, w1, acc[r]);
            acc[r] = fmaf(x.z, w2, acc[r]);
            acc[r] = fmaf(x.w, w3, acc[r]);
        }
    }
#pragma unroll
    for (int r = 0; r < 8; ++r) {
        const float a = acc[r];
        sg[g][r][u] = (g == 1) ? tanhf(a) : sigmoidf_(a);
    }
    __syncthreads();
    if (tid < 128) {
#pragma unroll
        for (int r = 0; r < 8; ++r) {
            const float i_ = sg[0][r][u];
            const float g_ = sg[1][r][u];
            const float o_ = sg[2][r][u];
            const float h = o_ * tanhf(i_ * g_);
            Ah[(size_t)(bt0 + r) * 128 + u] =
                __builtin_bit_cast(unsigned short, (_Float16)h);
        }
    }
}

// ---------------------------------------------------------------------------
// K6a: transpose + fp16-convert Wfc (128 x 32000, N-contig)
//      -> Bt (32000 x 128 fp16, K-contig).  grid 500 blocks, 256 threads.
// ---------------------------------------------------------------------------
__global__ __launch_bounds__(256) void k_cvtB(
    const float* __restrict__ Wfc, unsigned short* __restrict__ Bt)
{
    __shared__ __align__(16) unsigned short sH[64][136];
    const int n0 = blockIdx.x * 64;
    const int tid = threadIdx.x;
    const int kk = tid >> 4;       // 0..15
    const int n4 = tid & 15;       // 0..15

#pragma unroll
    for (int p = 0; p < 8; ++p) {
        const int k = p * 16 + kk;
        const float4 v = *(const float4*)&Wfc[(size_t)k * VOUT + n0 + n4 * 4];
        sH[n4 * 4 + 0][k] = __builtin_bit_cast(unsigned short, (_Float16)v.x);
        sH[n4 * 4 + 1][k] = __builtin_bit_cast(unsigned short, (_Float16)v.y);
        sH[n4 * 4 + 2][k] = __builtin_bit_cast(unsigned short, (_Float16)v.z);
        sH[n4 * 4 + 3][k] = __builtin_bit_cast(unsigned short, (_Float16)v.w);
    }
    __syncthreads();

    const int r0 = tid >> 4;
    const int l8 = (tid & 15) * 8;
#pragma unroll
    for (int p = 0; p < 4; ++p) {
        const int r = p * 16 + r0;
        *(uint4*)&Bt[(size_t)(n0 + r) * 128 + l8] = *(const uint4*)&sH[r][l8];
    }
}

// ---------------------------------------------------------------------------
// K6b: output GEMM  C(2048,32000) = Ah(2048,128) @ Bt^T + bfc, f16 MFMA.
// Block tile 128x128, 4 waves (2x2), each wave 64x64 = 4x4 tiles of 16x16.
// ---------------------------------------------------------------------------
__global__ __launch_bounds__(256) void k_out_f16(
    const unsigned short* __restrict__ Ah,   // 2048 x 128 fp16
    const unsigned short* __restrict__ Bt,   // 32000 x 128 fp16
    const float* __restrict__ bias, float* __restrict__ C)
{
    const int tid  = threadIdx.x;
    const int wave = tid >> 6;
    const int lane = tid & 63;
    const int wm = wave >> 1, wn = wave & 1;
    const int rb = blockIdx.y * 128 + wm * 64;
    const int cb = blockIdx.x * 128 + wn * 64;
    const int lm = lane & 15;
    const int quad = lane >> 4;

    floatx4 acc[4][4];
#pragma unroll
    for (int nt = 0; nt < 4; ++nt) {
        const float bv = bias[cb + nt * 16 + lm];
#pragma unroll
        for (int mt = 0; mt < 4; ++mt)
            acc[mt][nt] = (floatx4){bv, bv, bv, bv};
    }

    const unsigned short* pA = Ah + (size_t)(rb + lm) * 128 + quad * 8;
    const unsigned short* pB = Bt + (size_t)(cb + lm) * 128 + quad * 8;

#pragma unroll
    for (int kc = 0; kc < 128; kc += 32) {
        half8 af[4], bfr[4];
#pragma unroll
        for (int mt = 0; mt < 4; ++mt)
            af[mt] = *(const half8*)(pA + mt * (16 * 128) + kc);
#pragma unroll
        for (int nt = 0; nt < 4; ++nt)
            bfr[nt] = *(const half8*)(pB + nt * (16 * 128) + kc);
#pragma unroll
        for (int mt = 0; mt < 4; ++mt)
#pragma unroll
            for (int nt = 0; nt < 4; ++nt)
                acc[mt][nt] = __builtin_amdgcn_mfma_f32_16x16x32_f16(
                    af[mt], bfr[nt], acc[mt][nt], 0, 0, 0);
    }

#pragma unroll
    for (int mt = 0; mt < 4; ++mt) {
        const int r0 = rb + mt * 16 + quad * 4;
#pragma unroll
        for (int nt = 0; nt < 4; ++nt) {
            const int col = cb + nt * 16 + lm;
            float* Cp = C + (size_t)r0 * VOUT + col;
#pragma unroll
            for (int r = 0; r < 4; ++r)
                Cp[(size_t)r * VOUT] = acc[mt][nt][r];
        }
    }
}

// ---------------------------------------------------------------------------
extern "C" void kernel_launch(void* const* d_in, const int* in_sizes, int n_in,
                              void* d_out, int out_size, void* d_ws, size_t ws_size,
                              hipStream_t stream) {
    (void)in_sizes; (void)n_in; (void)out_size; (void)ws_size;
    const int*   source  = (const int*)  d_in[0];
    const int*   target  = (const int*)  d_in[1];
    const float* src_emb = (const float*)d_in[2];
    const float* tgt_emb = (const float*)d_in[3];
    const float* Wf      = (const float*)d_in[4];
    const float* Uf      = (const float*)d_in[5];
    const float* bf      = (const float*)d_in[6];
    const float* Wb      = (const float*)d_in[7];
    const float* Ub      = (const float*)d_in[8];
    const float* bb      = (const float*)d_in[9];
    const float* W1      = (const float*)d_in[10];
    const float* b1      = (const float*)d_in[11];
    const float* W2      = (const float*)d_in[12];
    const float* b2      = (const float*)d_in[13];
    const float* Vw      = (const float*)d_in[14];
    const float* Vb      = (const float*)d_in[15];
    const float* Wd      = (const float*)d_in[16];
    const float* bd      = (const float*)d_in[17];
    const float* Wfc     = (const float*)d_in[18];
    const float* bfc     = (const float*)d_in[19];
    float* out = (float*)d_out;

    // workspace layout (float offsets)
    float* ws     = (float*)d_ws;
    float* Zf     = ws;                      // 1048576 f (dead after k_scan)
    float* Zb     = Zf + 1048576;            // 1048576 f (dead after k_scan)
    float* enc    = Zb + 1048576;            // 524288 f
    float* hidden = enc + 524288;            // 1024 f
    float* q2     = hidden + 1024;           // 2048 f
    float* scores = q2 + 2048;               // 8192 f
    float* ctx    = scores + 8192;           // 1024 f
    unsigned short* Ah = (unsigned short*)(ctx + 1024);  // 2048*128 fp16
    unsigned short* Bt = (unsigned short*)Zf;            // aliases dead Zf/Zb

    k_embed_gemm<<<1024, 256, 0, stream>>>(source, src_emb, Wf, bf, Wb, bb, Zf, Zb);
    k_scan<<<32, 64, 0, stream>>>(Zf, Zb, Uf, Ub, enc, hidden);
    k_q<<<16, 128, 0, stream>>>(hidden, W1, b1, b2, q2);
    k_score<<<8192, 128, 0, stream>>>(enc, q2, W2, Vw, Vb, scores);
    k_softmax_ctx<<<16, 512, 0, stream>>>(scores, enc, ctx);
    k_cvtB<<<500, 256, 0, stream>>>(Wfc, Bt);   // after k_scan: Zf/Zb dead
    k_dec<<<256, 384, 0, stream>>>(target, tgt_emb, ctx, Wd, bd, Ah);
    k_out_f16<<<dim3(250, 16), 256, 0, stream>>>(Ah, Bt, bfc, out);
}